// Round 4
// baseline (842.622 us; speedup 1.0000x reference)
//
#include <hip/hip_runtime.h>
#include <math.h>

typedef unsigned short ushort_t;
typedef __bf16 v8bf __attribute__((ext_vector_type(8)));
typedef __bf16 v4bf __attribute__((ext_vector_type(4)));
typedef float  v4f  __attribute__((ext_vector_type(4)));
typedef float  f32x4 __attribute__((ext_vector_type(4)));

#define BATCH 4
#define SEQ 4096
#define DM 1024
#define NS 256
#define MROWS (BATCH*SEQ)   // 16384

#define NCH 128
#define CL (SEQ/NCH)        // 32

#define BM 64               // fused rows/block = 2 scan chunks
#define BK1 64              // gemm1 K-step
#define BK2 64              // gemm2 K-step
#define SST 257             // fp32 scan-stage stride (bank stagger)

#define MAGICF(i) (0x5A170000u ^ (unsigned)(i))

typedef __attribute__((address_space(1))) void as1_void;
typedef __attribute__((address_space(3))) void as3_void;

__device__ __forceinline__ void gl_lds16(const void* g, void* l) {
    __builtin_amdgcn_global_load_lds((as1_void*)g, (as3_void*)l, 16, 0, 0);
}

__device__ __forceinline__ ushort_t f2bf(float f) {
    unsigned u = __builtin_bit_cast(unsigned, f);
    u += 0x7fff + ((u >> 16) & 1);          // RNE
    return (ushort_t)(u >> 16);
}

__device__ __forceinline__ float sigm(float x) { return 1.0f / (1.0f + expf(-x)); }

__device__ __forceinline__ float powk(int e, float l1, float l2, float l4,
                                      float l8, float l16) {
    float w = 1.0f;
    if (e & 1)  w *= l1;
    if (e & 2)  w *= l2;
    if (e & 4)  w *= l4;
    if (e & 8)  w *= l8;
    if (e & 16) w *= l16;
    return w;
}

// ---------------------------------------------------------------------------
// Fully fused SSM layer. 256 blocks x 512 threads, 1 block/CU.
//   A) gemm1: Bu-tile 64x256 (BK=64, dbuf, XOR-swizzled LDS), acc in regs.
//   B) chunk-finals cf -> global; publish per-chunk flag (release, agent).
//      Decoupled look-back: spin (relaxed, batched) on flags of LOWER blocks
//      only (dispatch-order-safe), fence, Horner carry over cf.
//   C) scan replay in LDS (fp32 S -> swizzled bf16 hs); Bu/hs never hit HBM.
//   D) gemm2: y = hs . Cw^T in 8 col-panels of 128 (BK=64, dbuf, swizzled).
// Workspace poison safety: flags compared against per-slot magic; stale-magic
// replays read identical (deterministic) cf values.
// ---------------------------------------------------------------------------
__global__ __launch_bounds__(512)
void ssm_fused(const float* __restrict__ A,       // u [M,DM] fp32
               const ushort_t* __restrict__ Bw,   // bf16 [NS,DM]
               const ushort_t* __restrict__ Cw,   // bf16 [DM,NS]
               const float* __restrict__ ll,      // [NS]
               float* __restrict__ cf,            // [BATCH,NCH,NS]
               unsigned* __restrict__ flags,      // [BATCH*NCH]
               float* __restrict__ Y,             // [M,DM] fp32
               const float* __restrict__ Dvec,
               const float* __restrict__ U)
{
    const int K = DM;
    __shared__ __align__(16) union {
        struct { ushort_t As[2][BM*BK1]; ushort_t Bs[2][NS*BK1]; } a;   // 80 KB
        struct { ushort_t hs[BM*NS]; ushort_t Bsw[2][128*BK2];
                 float S[BM*SST]; } b;                                   // 128.25 KB
    } L;

    const int tid  = threadIdx.x;
    const int lane = tid & 63;
    const int wave = tid >> 6;
    const int wr = wave >> 2;        // m-half: rows wr*32..wr*32+31
    const int wc = wave & 3;         // n-quadrant: cols wc*64..wc*64+63
    const int fr = lane & 15;
    const int fq = lane >> 4;
    const int m0 = blockIdx.x * BM;
    const int b_idx = m0 >> 12;
    const int c0    = (m0 & 4095) >> 5;    // even; block owns chunks c0, c0+1

    // ================= phase A: gemm1 =================
    // A staging: 64x64 fp32 = 1024 float4, 2/thread; swizzled ds_write.
    int arow[2], ac4[2], aoff[2];
    #pragma unroll
    for (int j = 0; j < 2; ++j) {
        int cid = j*512 + tid;
        arow[j] = cid >> 4;
        ac4[j]  = (cid & 15) * 4;
        aoff[j] = arow[j]*BK1 + (((ac4[j] >> 3) ^ (arow[j] & 7)) * 8) + (ac4[j] & 4);
    }
    // B staging: 256x64 bf16 = 2048 x16B chunks, 4/thread; linear LDS dst,
    // inverse-swizzled global source column.
    int brow[4], bcs[4];
    #pragma unroll
    for (int j = 0; j < 4; ++j) {
        int cid = j*512 + tid;
        brow[j] = cid >> 3;
        bcs[j]  = ((cid & 7) ^ (brow[j] & 7)) * 8;
    }

    f32x4 acc[2][4] = {};   // rows wr*32+mi*16.., cols wc*64+ni*16..
    v4f areg[2];

    #pragma unroll
    for (int j = 0; j < 2; ++j)
        areg[j] = *(const v4f*)&A[(size_t)(m0 + arow[j])*K + ac4[j]];
    #pragma unroll
    for (int j = 0; j < 4; ++j)
        gl_lds16(&Bw[(size_t)brow[j]*K + bcs[j]], &L.a.Bs[0][(j*512 + tid)*8]);

    const int NIT = K / BK1;   // 16
    for (int it = 0; it < NIT; ++it) {
        const int cur = it & 1;
        #pragma unroll
        for (int j = 0; j < 2; ++j)
            *(v4bf*)&L.a.As[cur][aoff[j]] = __builtin_convertvector(areg[j], v4bf);
        __syncthreads();

        if (it + 1 < NIT) {
            const int k1 = (it + 1) * BK1;
            #pragma unroll
            for (int j = 0; j < 4; ++j)
                gl_lds16(&Bw[(size_t)brow[j]*K + k1 + bcs[j]],
                         &L.a.Bs[cur^1][(j*512 + tid)*8]);
            #pragma unroll
            for (int j = 0; j < 2; ++j)
                areg[j] = *(const v4f*)&A[(size_t)(m0 + arow[j])*K + k1 + ac4[j]];
        }

        #pragma unroll
        for (int kk = 0; kk < 2; ++kk) {
            v8bf af[2], bf[4];
            #pragma unroll
            for (int mi = 0; mi < 2; ++mi) {
                const int r  = wr*32 + mi*16 + fr;
                const int ch = (kk*4 + fq) ^ (r & 7);
                af[mi] = *reinterpret_cast<const v8bf*>(&L.a.As[cur][r*BK1 + ch*8]);
            }
            #pragma unroll
            for (int ni = 0; ni < 4; ++ni) {
                const int r  = wc*64 + ni*16 + fr;
                const int ch = (kk*4 + fq) ^ (r & 7);
                bf[ni] = *reinterpret_cast<const v8bf*>(&L.a.Bs[cur][r*BK1 + ch*8]);
            }
            #pragma unroll
            for (int mi = 0; mi < 2; ++mi)
                #pragma unroll
                for (int ni = 0; ni < 4; ++ni)
                    acc[mi][ni] = __builtin_amdgcn_mfma_f32_16x16x32_bf16(
                                      af[mi], bf[ni], acc[mi][ni], 0, 0, 0);
        }
    }
    __syncthreads();   // all frag reads done; As/Bs dead

    // Cw panel prefetch for gemm2 step 0 (Bsw disjoint from S/hs regions)
    #define STAGE_B(g, buf)                                                    \
        {                                                                      \
            const int p_ = (g) >> 2, ks_ = (g) & 3;                            \
            _Pragma("unroll")                                                  \
            for (int jj = 0; jj < 2; ++jj) {                                   \
                const int cid = jj*512 + tid;                                  \
                const int row_ = cid >> 3, kch_ = cid & 7;                     \
                const int koff_ = ks_*BK2 + ((kch_ ^ (row_ & 7)) * 8);         \
                gl_lds16(&Cw[(size_t)(p_*128 + row_)*NS + koff_],              \
                         &L.b.Bsw[buf][cid*8]);                                \
            }                                                                  \
        }
    STAGE_B(0, 0);

    // stage acc -> S (C/D layout: col=lane&15, row=fq*4+r)
    #pragma unroll
    for (int mi = 0; mi < 2; ++mi) {
        #pragma unroll
        for (int ni = 0; ni < 4; ++ni) {
            const int col = wc*64 + ni*16 + fr;
            #pragma unroll
            for (int r = 0; r < 4; ++r)
                L.b.S[(wr*32 + mi*16 + fq*4 + r)*SST + col] = acc[mi][ni][r];
        }
    }

    // chunk finals cf[b, c0+wr, n] = sum_t lam^(31-t) Bu[t,n]
    #pragma unroll
    for (int ni = 0; ni < 4; ++ni) {
        const int col = wc*64 + ni*16 + fr;
        const float l1  = sigm(ll[col]);
        const float l2  = l1*l1;
        const float l4  = l2*l2;
        const float l8  = l4*l4;
        const float l16 = l8*l8;
        float f = 0.0f;
        #pragma unroll
        for (int mi = 0; mi < 2; ++mi) {
            float w = powk(28 - mi*16 - fq*4, l1, l2, l4, l8, l16);
            f = fmaf(w, acc[mi][ni][3], f);
            w *= l1; f = fmaf(w, acc[mi][ni][2], f);
            w *= l1; f = fmaf(w, acc[mi][ni][1], f);
            w *= l1; f = fmaf(w, acc[mi][ni][0], f);
        }
        f += __shfl_xor(f, 16, 64);
        f += __shfl_xor(f, 32, 64);
        if (fq == 0)
            cf[((size_t)b_idx*NCH + c0 + wr)*NS + col] = f;
    }

    __threadfence();       // cf stores agent-visible
    __syncthreads();       // (also: S writes visible to all threads)
    if (tid == 0)
        __hip_atomic_store(&flags[b_idx*NCH + c0], MAGICF(b_idx*NCH + c0),
                           __ATOMIC_RELEASE, __HIP_MEMORY_SCOPE_AGENT);
    if (tid == 256)
        __hip_atomic_store(&flags[b_idx*NCH + c0 + 1], MAGICF(b_idx*NCH + c0 + 1),
                           __ATOMIC_RELEASE, __HIP_MEMORY_SCOPE_AGENT);

    // ================= phase B: look-back carry =================
    const int h2 = tid >> 8;         // block's chunk 0/1
    const int n  = tid & 255;        // state column
    const int cG = c0 + h2;          // need chunks [0, cG)
    const int bN = b_idx*NCH;
    const float lam = sigm(ll[n]);
    float lamL = lam;
    #pragma unroll
    for (int i = 0; i < 5; ++i) lamL *= lamL;   // lam^32

    const unsigned* flg = flags + bN;
    const float* cfb = cf + (size_t)bN*NS + n;
    float x = 0.0f;
    int cc = 0;
    for (; cc + 16 <= cG; cc += 16) {
        bool all;
        do {
            all = true;
            #pragma unroll
            for (int j = 0; j < 16; ++j) {
                unsigned v = __hip_atomic_load(&flg[cc + j], __ATOMIC_RELAXED,
                                               __HIP_MEMORY_SCOPE_AGENT);
                all = all && (v == MAGICF(bN + cc + j));
            }
            if (!all) __builtin_amdgcn_s_sleep(8);
        } while (!all);
        __threadfence();
        float vv[16];
        #pragma unroll
        for (int j = 0; j < 16; ++j) vv[j] = cfb[(size_t)(cc + j)*NS];
        #pragma unroll
        for (int j = 0; j < 16; ++j) x = fmaf(lamL, x, vv[j]);
    }
    for (; cc < cG; ++cc) {
        while (__hip_atomic_load(&flg[cc], __ATOMIC_RELAXED,
                                 __HIP_MEMORY_SCOPE_AGENT) != MAGICF(bN + cc))
            __builtin_amdgcn_s_sleep(8);
        __threadfence();
        x = fmaf(lamL, x, cfb[(size_t)cc*NS]);
    }

    // ================= phase C: scan replay (LDS) =================
    float h = x;
    #pragma unroll
    for (int t = 0; t < CL; ++t) {
        const int row = h2*32 + t;
        h = fmaf(lam, h, L.b.S[row*SST + n]);
        L.b.hs[row*NS + (((n >> 3) ^ (row & 7)) << 3) + (n & 7)] = f2bf(h);
    }
    __syncthreads();   // hs complete; Bsw[0] drained

    // ================= phase D: gemm2, 8 panels x 4 k-steps =================
    const int wm = wr;               // rows wm*32..; cols (panel) nq*32..
    const int nq = wc;
    int g = 0;
    for (int p = 0; p < 8; ++p) {
        f32x4 acc2[2][2] = {};
        for (int ks = 0; ks < 4; ++ks, ++g) {
            const int cur = g & 1;
            if (g) __syncthreads();
            if (g + 1 < 32) STAGE_B(g + 1, cur ^ 1);

            #pragma unroll
            for (int kk = 0; kk < 2; ++kk) {
                v8bf af[2], bf[2];
                #pragma unroll
                for (int mi = 0; mi < 2; ++mi) {
                    const int r  = wm*32 + mi*16 + fr;
                    const int ch = (ks*8 + kk*4 + fq) ^ (r & 7);
                    af[mi] = *reinterpret_cast<const v8bf*>(&L.b.hs[r*NS + ch*8]);
                }
                #pragma unroll
                for (int ni = 0; ni < 2; ++ni) {
                    const int rn = nq*32 + ni*16 + fr;
                    const int ch = (kk*4 + fq) ^ (rn & 7);
                    bf[ni] = *reinterpret_cast<const v8bf*>(&L.b.Bsw[cur][rn*BK2 + ch*8]);
                }
                #pragma unroll
                for (int mi = 0; mi < 2; ++mi)
                    #pragma unroll
                    for (int ni = 0; ni < 2; ++ni)
                        acc2[mi][ni] = __builtin_amdgcn_mfma_f32_16x16x32_bf16(
                                           af[mi], bf[ni], acc2[mi][ni], 0, 0, 0);
            }
        }
        // panel epilogue (C/D layout: col=lane&15, row=fq*4+reg)
        #pragma unroll
        for (int ni = 0; ni < 2; ++ni) {
            const int gcol = p*128 + nq*32 + ni*16 + fr;
            const float d = Dvec[gcol];
            #pragma unroll
            for (int mi = 0; mi < 2; ++mi) {
                #pragma unroll
                for (int r = 0; r < 4; ++r) {
                    const int grow = m0 + wm*32 + mi*16 + fq*4 + r;
                    const size_t idx = (size_t)grow*DM + gcol;
                    float v = acc2[mi][ni][r];
                    if (d != 0.0f) v = fmaf(d, U[idx], v);   // no load when D==0
                    Y[idx] = v;
                }
            }
        }
    }
    #undef STAGE_B
}

// ---------------------------------------------------------------------------
__global__ __launch_bounds__(256)
void cvt_w(const float4* __restrict__ Bw, const float4* __restrict__ Cw,
           ushort_t* __restrict__ Bo, ushort_t* __restrict__ Co)
{
    const int i = blockIdx.x * 256 + threadIdx.x;
    const float4* src = blockIdx.y ? Cw : Bw;
    ushort_t*     dst = blockIdx.y ? Co : Bo;
    float4 v = src[i];
    ushort4 o;
    o.x = f2bf(v.x); o.y = f2bf(v.y); o.z = f2bf(v.z); o.w = f2bf(v.w);
    *(ushort4*)&dst[4*(size_t)i] = o;
}

// ---------------------------------------------------------------------------
extern "C" void kernel_launch(void* const* d_in, const int* in_sizes, int n_in,
                              void* d_out, int out_size, void* d_ws, size_t ws_size,
                              hipStream_t stream) {
    const float* u          = (const float*)d_in[0];
    const float* log_lambda = (const float*)d_in[1];
    const float* B_w        = (const float*)d_in[2];
    const float* C_w        = (const float*)d_in[3];
    const float* Dv         = (const float*)d_in[4];
    float* y  = (float*)d_out;

    char* w = (char*)d_ws;
    ushort_t* Bw16  = (ushort_t*)w;                    // 512 KB
    ushort_t* Cw16  = (ushort_t*)(w + 524288);         // 512 KB
    float*    cf    = (float*)(w + 1048576);           // 512 KB
    unsigned* flags = (unsigned*)(w + 1572864);        // 2 KB

    // 0) weight conversions
    cvt_w<<<dim3(256, 2), dim3(256), 0, stream>>>(
        (const float4*)B_w, (const float4*)C_w, Bw16, Cw16);

    // 1) fully fused: gemm1 + cf/look-back + scan + gemm2
    ssm_fused<<<dim3(MROWS/BM), dim3(512), 0, stream>>>(
        u, Bw16, Cw16, log_lambda, cf, flags, y, Dv, u);
}

// Round 5
// 163.082 us; speedup vs baseline: 5.1668x; 5.1668x over previous
//
#include <hip/hip_runtime.h>
#include <math.h>

typedef unsigned short ushort_t;
typedef __bf16 v8bf __attribute__((ext_vector_type(8)));
typedef __bf16 v4bf __attribute__((ext_vector_type(4)));
typedef float  v4f  __attribute__((ext_vector_type(4)));
typedef float  f32x4 __attribute__((ext_vector_type(4)));

#define BATCH 4
#define SEQ 4096
#define DM 1024
#define NS 256
#define MROWS (BATCH*SEQ)   // 16384

#define NCH 128
#define CL (SEQ/NCH)        // 32

#define BK1 64              // gemm1 K-step
#define BM2 32              // gemm2 rows/block = 1 scan chunk
#define BK2 64              // gemm2 K-step

typedef __attribute__((address_space(1))) void as1_void;
typedef __attribute__((address_space(3))) void as3_void;

__device__ __forceinline__ void gl_lds16(const void* g, void* l) {
    __builtin_amdgcn_global_load_lds((as1_void*)g, (as3_void*)l, 16, 0, 0);
}

__device__ __forceinline__ ushort_t f2bf(float f) {
    unsigned u = __builtin_bit_cast(unsigned, f);
    u += 0x7fff + ((u >> 16) & 1);          // RNE
    return (ushort_t)(u >> 16);
}

__device__ __forceinline__ float sigm(float x) { return 1.0f / (1.0f + expf(-x)); }

__device__ __forceinline__ float powk(int e, float l1, float l2, float l4,
                                      float l8, float l16) {
    float w = 1.0f;
    if (e & 1)  w *= l1;
    if (e & 2)  w *= l2;
    if (e & 4)  w *= l4;
    if (e & 8)  w *= l8;
    if (e & 16) w *= l16;
    return w;
}

// ---------------------------------------------------------------------------
// GEMM1 (full-K): Bu = u . B_w^T, tile 32(m) x 256(n), BK=64, double-buffered,
// XOR-swizzled LDS. A-prefetch is 2 iterations deep (named areg0/areg1, loop
// unrolled x2 so all register indices are compile-time) and issued BEFORE the
// global_load_lds, so the ds_write at the top of each iteration waits only on
// a long-retired load (vmcnt(N) with N large -> no stall). grid 512 = 2
// independent blocks/CU. Chunk-final cf computed in-register.
// ---------------------------------------------------------------------------
__global__ __launch_bounds__(256)
void gemm1_fused(const float* __restrict__ A,      // u [M,K] fp32
                 const ushort_t* __restrict__ B,   // Bw16 [NS,K] bf16
                 float* __restrict__ Bu,           // [M,NS] fp32
                 const float* __restrict__ ll,     // [NS]
                 float* __restrict__ cf)           // [BATCH,NCH,NS]
{
    const int K = DM;
    __shared__ __align__(16) ushort_t As[2][32*BK1];    // 2 x 4 KB
    __shared__ __align__(16) ushort_t Bs[2][NS*BK1];    // 2 x 32 KB

    const int tid  = threadIdx.x;
    const int lane = tid & 63;
    const int wave = tid >> 6;       // n-quadrant: cols wave*64..wave*64+63
    const int m0   = blockIdx.x * 32;

    const int fr = lane & 15;
    const int fq = lane >> 4;

    // A staging: 32x64 fp32 = 512 float4 chunks, 2/thread; swizzled ds_write.
    int arow[2], ac4[2], aoff[2];
    #pragma unroll
    for (int j = 0; j < 2; ++j) {
        int cid = j*256 + tid;
        arow[j] = cid >> 4;
        ac4[j]  = (cid & 15) * 4;
        aoff[j] = arow[j]*BK1 + (((ac4[j] >> 3) ^ (arow[j] & 7)) * 8) + (ac4[j] & 4);
    }
    // B staging: 256x64 bf16 = 2048 x16B chunks, 8/thread; linear LDS dst,
    // inverse-swizzled global source column.
    int brow[8], bcs[8];
    #pragma unroll
    for (int j = 0; j < 8; ++j) {
        int cid = j*256 + tid;
        brow[j] = cid >> 3;
        bcs[j]  = ((cid & 7) ^ (brow[j] & 7)) * 8;
    }

    f32x4 acc[2][4] = {};   // [mi][ni] : m = mi*16.., n = wave*64 + ni*16..
    v4f areg0[2], areg1[2];

    const int NIT = K / BK1;   // 16 (even)

    // ---- prologue: A k=0, B k=0, A k=1 ----
    #pragma unroll
    for (int j = 0; j < 2; ++j)
        areg0[j] = *(const v4f*)&A[(size_t)(m0 + arow[j])*K + ac4[j]];
    #pragma unroll
    for (int j = 0; j < 8; ++j)
        gl_lds16(&B[(size_t)brow[j]*K + bcs[j]], &Bs[0][(j*256 + tid)*8]);
    #pragma unroll
    for (int j = 0; j < 2; ++j)
        areg1[j] = *(const v4f*)&A[(size_t)(m0 + arow[j])*K + BK1 + ac4[j]];

    // one double-step per loop iteration; P = buffer parity (compile-time)
    #define G1_STEP(IT, P, AREG)                                               \
    {                                                                          \
        _Pragma("unroll")                                                      \
        for (int j = 0; j < 2; ++j)                                            \
            *(v4bf*)&As[P][aoff[j]] = __builtin_convertvector(AREG[j], v4bf);  \
        __syncthreads();                                                       \
        if ((IT) + 2 < NIT) {                                                  \
            const int k2 = ((IT) + 2) * BK1;                                   \
            _Pragma("unroll")                                                  \
            for (int j = 0; j < 2; ++j)                                        \
                AREG[j] = *(const v4f*)&A[(size_t)(m0 + arow[j])*K + k2 + ac4[j]]; \
        }                                                                      \
        if ((IT) + 1 < NIT) {                                                  \
            const int k1 = ((IT) + 1) * BK1;                                   \
            _Pragma("unroll")                                                  \
            for (int j = 0; j < 8; ++j)                                        \
                gl_lds16(&B[(size_t)brow[j]*K + k1 + bcs[j]],                  \
                         &Bs[(P)^1][(j*256 + tid)*8]);                         \
        }                                                                      \
        _Pragma("unroll")                                                      \
        for (int kk = 0; kk < 2; ++kk) {                                       \
            v8bf af[2], bf[4];                                                 \
            _Pragma("unroll")                                                  \
            for (int mi = 0; mi < 2; ++mi) {                                   \
                const int r  = mi*16 + fr;                                     \
                const int ch = (kk*4 + fq) ^ (r & 7);                          \
                af[mi] = *reinterpret_cast<const v8bf*>(&As[P][r*BK1 + ch*8]); \
            }                                                                  \
            _Pragma("unroll")                                                  \
            for (int ni = 0; ni < 4; ++ni) {                                   \
                const int r  = wave*64 + ni*16 + fr;                           \
                const int ch = (kk*4 + fq) ^ (r & 7);                          \
                bf[ni] = *reinterpret_cast<const v8bf*>(&Bs[P][r*BK1 + ch*8]); \
            }                                                                  \
            _Pragma("unroll")                                                  \
            for (int mi = 0; mi < 2; ++mi)                                     \
                _Pragma("unroll")                                              \
                for (int ni = 0; ni < 4; ++ni)                                 \
                    acc[mi][ni] = __builtin_amdgcn_mfma_f32_16x16x32_bf16(     \
                                      af[mi], bf[ni], acc[mi][ni], 0, 0, 0);   \
        }                                                                      \
    }

    for (int it = 0; it < NIT; it += 2) {
        G1_STEP(it,     0, areg0);
        G1_STEP(it + 1, 1, areg1);
    }
    #undef G1_STEP

    // ---- write Bu. C/D layout: col=lane&15, row=(lane>>4)*4+reg ----
    #pragma unroll
    for (int mi = 0; mi < 2; ++mi) {
        #pragma unroll
        for (int ni = 0; ni < 4; ++ni) {
            const int col = wave*64 + ni*16 + fr;
            #pragma unroll
            for (int r = 0; r < 4; ++r)
                Bu[(size_t)(m0 + mi*16 + fq*4 + r)*NS + col] = acc[mi][ni][r];
        }
    }

    // ---- chunk final: cf[b,c,n] = sum_t lam^(31-t) Bu[t,n]; block = chunk ----
    const int b_idx = m0 >> 12;            // 4096 rows per batch
    const int c_idx = (m0 & 4095) >> 5;    // 32 rows per chunk

    #pragma unroll
    for (int ni = 0; ni < 4; ++ni) {
        const int col = wave*64 + ni*16 + fr;
        const float l1  = sigm(ll[col]);
        const float l2  = l1*l1;
        const float l4  = l2*l2;
        const float l8  = l4*l4;
        const float l16 = l8*l8;
        float f = 0.0f;
        #pragma unroll
        for (int mi = 0; mi < 2; ++mi) {
            float w = powk(28 - mi*16 - fq*4, l1, l2, l4, l8, l16);
            f = fmaf(w, acc[mi][ni][3], f);
            w *= l1; f = fmaf(w, acc[mi][ni][2], f);
            w *= l1; f = fmaf(w, acc[mi][ni][1], f);
            w *= l1; f = fmaf(w, acc[mi][ni][0], f);
        }
        f += __shfl_xor(f, 16, 64);
        f += __shfl_xor(f, 32, 64);
        if (fq == 0)
            cf[((size_t)b_idx*NCH + c_idx)*NS + col] = f;
    }
}

// ---------------------------------------------------------------------------
// GEMM2+scan fused, 32-row blocks (1 chunk), 256 thr, grid 512 = 2 blocks/CU.
//   1) v[32] = Bu column (coalesced per row) -> registers, issued first so
//      HBM latency hides under the carry Horner (no LDS staging).
//   2) carry Horner over cf (L2-resident), scan replay -> swizzled bf16 hs
//      in LDS (16 KB). hs never touches HBM.
//   3) GEMM vs Cw in 8 column panels of 128, BK=64 dbuf (32 KB), swizzled.
// LDS total 48 KB.
// ---------------------------------------------------------------------------
__global__ __launch_bounds__(256)
void gemm2_scan(const float* __restrict__ Bu,     // [M,NS] fp32
                const ushort_t* __restrict__ Cw,  // Cw16 [DM,NS] bf16
                const float* __restrict__ ll,     // [NS]
                const float* __restrict__ cf,     // [BATCH,NCH,NS]
                float* __restrict__ Y,            // [M,DM] fp32
                const float* __restrict__ Dvec,
                const float* __restrict__ U)
{
    __shared__ __align__(16) ushort_t hsS[BM2*NS];        // 16 KB (swizzled)
    __shared__ __align__(16) ushort_t Bsw[2][128*BK2];    // 32 KB

    const int tid  = threadIdx.x;
    const int lane = tid & 63;
    const int wave = tid >> 6;       // n-quadrant within panel: cols wave*32..
    const int fr = lane & 15;
    const int fq = lane >> 4;
    const int m0 = blockIdx.x * BM2;
    const int n  = tid;              // state column 0..255

    // ---- 1) Bu column -> regs (issued first; 32 coalesced rows) ----
    const float* bp = Bu + (size_t)m0*NS + n;
    float v[CL];
    #pragma unroll
    for (int t = 0; t < CL; ++t)
        v[t] = bp[(size_t)t*NS];

    // ---- prefetch first Cw panel k-step (pre-swizzled source, linear dst) ----
    #define STAGE_B(g, buf)                                                    \
        {                                                                      \
            const int p_ = (g) >> 2, ks_ = (g) & 3;                            \
            _Pragma("unroll")                                                  \
            for (int jj = 0; jj < 4; ++jj) {                                   \
                const int cid = jj*256 + tid;                                  \
                const int row_ = cid >> 3, kch_ = cid & 7;                     \
                const int koff_ = ks_*BK2 + ((kch_ ^ (row_ & 7)) * 8);         \
                gl_lds16(&Cw[(size_t)(p_*128 + row_)*NS + koff_],              \
                         &Bsw[buf][cid*8]);                                    \
            }                                                                  \
        }
    STAGE_B(0, 0);

    // ---- 2) carry Horner over cf ----
    const int b_idx = m0 >> 12;
    const int cG    = (m0 & 4095) >> 5;    // need chunks [0, cG)
    const float lam = sigm(ll[n]);
    float lamL = lam;
    #pragma unroll
    for (int i = 0; i < 5; ++i) lamL *= lamL;   // lam^32

    const float* cfb = cf + (size_t)b_idx*NCH*NS + n;
    float x = 0.0f;
    int cc = 0;
    for (; cc + 16 <= cG; cc += 16) {
        float vv[16];
        #pragma unroll
        for (int j = 0; j < 16; ++j) vv[j] = cfb[(size_t)(cc + j)*NS];
        #pragma unroll
        for (int j = 0; j < 16; ++j) x = fmaf(lamL, x, vv[j]);
    }
    for (; cc < cG; ++cc) x = fmaf(lamL, x, cfb[(size_t)cc*NS]);

    // ---- scan replay; hs written bf16 with (row&7) chunk-XOR swizzle ----
    float h = x;
    #pragma unroll
    for (int t = 0; t < CL; ++t) {
        h = fmaf(lam, h, v[t]);
        hsS[t*NS + (((n >> 3) ^ (t & 7)) << 3) + (n & 7)] = f2bf(h);
    }
    __syncthreads();   // hs complete; Bsw[0] staged (drained by barrier)

    // ---- 3) GEMM: 8 panels x (K=256 in 4 steps of BK2=64), dbuf ----
    int g = 0;
    for (int p = 0; p < 8; ++p) {
        f32x4 acc[2][2] = {};
        for (int ks = 0; ks < 4; ++ks, ++g) {
            const int cur = g & 1;
            if (g) __syncthreads();
            if (g + 1 < 32) STAGE_B(g + 1, cur ^ 1);

            #pragma unroll
            for (int kk = 0; kk < 2; ++kk) {
                v8bf af[2], bf[2];
                #pragma unroll
                for (int mi = 0; mi < 2; ++mi) {
                    const int r  = mi*16 + fr;
                    const int ch = (ks*8 + kk*4 + fq) ^ (r & 7);
                    af[mi] = *reinterpret_cast<const v8bf*>(&hsS[r*NS + ch*8]);
                }
                #pragma unroll
                for (int ni = 0; ni < 2; ++ni) {
                    const int rn = wave*32 + ni*16 + fr;
                    const int ch = (kk*4 + fq) ^ (rn & 7);
                    bf[ni] = *reinterpret_cast<const v8bf*>(&Bsw[cur][rn*BK2 + ch*8]);
                }
                #pragma unroll
                for (int mi = 0; mi < 2; ++mi)
                    #pragma unroll
                    for (int ni = 0; ni < 2; ++ni)
                        acc[mi][ni] = __builtin_amdgcn_mfma_f32_16x16x32_bf16(
                                          af[mi], bf[ni], acc[mi][ni], 0, 0, 0);
            }
        }
        // panel epilogue (C/D layout: col=lane&15, row=fq*4+reg)
        #pragma unroll
        for (int ni = 0; ni < 2; ++ni) {
            const int gcol = p*128 + wave*32 + ni*16 + fr;
            const float d = Dvec[gcol];
            #pragma unroll
            for (int mi = 0; mi < 2; ++mi) {
                #pragma unroll
                for (int r = 0; r < 4; ++r) {
                    const int grow = m0 + mi*16 + fq*4 + r;
                    const size_t idx = (size_t)grow*DM + gcol;
                    float vo = acc[mi][ni][r];
                    if (d != 0.0f) vo = fmaf(d, U[idx], vo);   // no load when D==0
                    Y[idx] = vo;
                }
            }
        }
    }
    #undef STAGE_B
}

// ---------------------------------------------------------------------------
__global__ __launch_bounds__(256)
void cvt_w(const float4* __restrict__ Bw, const float4* __restrict__ Cw,
           ushort_t* __restrict__ Bo, ushort_t* __restrict__ Co)
{
    const int i = blockIdx.x * 256 + threadIdx.x;
    const float4* src = blockIdx.y ? Cw : Bw;
    ushort_t*     dst = blockIdx.y ? Co : Bo;
    float4 v = src[i];
    ushort4 o;
    o.x = f2bf(v.x); o.y = f2bf(v.y); o.z = f2bf(v.z); o.w = f2bf(v.w);
    *(ushort4*)&dst[4*(size_t)i] = o;
}

// ---------------------------------------------------------------------------
extern "C" void kernel_launch(void* const* d_in, const int* in_sizes, int n_in,
                              void* d_out, int out_size, void* d_ws, size_t ws_size,
                              hipStream_t stream) {
    const float* u          = (const float*)d_in[0];
    const float* log_lambda = (const float*)d_in[1];
    const float* B_w        = (const float*)d_in[2];
    const float* C_w        = (const float*)d_in[3];
    const float* Dv         = (const float*)d_in[4];
    float* y  = (float*)d_out;

    char* w = (char*)d_ws;
    float*    Bu   = (float*)w;                        // 16.78 MB
    ushort_t* Bw16 = (ushort_t*)(w + 16777216);        // 512 KB
    ushort_t* Cw16 = (ushort_t*)(w + 17301504);        // 512 KB
    float*    cf   = (float*)(w + 17825792);           // 512 KB

    dim3 blk(256);

    // 0) weight conversions
    cvt_w<<<dim3(256, 2), blk, 0, stream>>>((const float4*)B_w, (const float4*)C_w,
                                            Bw16, Cw16);

    // 1) Bu = u . B_w^T (full K, swizzled LDS, 2-deep A prefetch),
    //    fused cvt + chunk finals
    gemm1_fused<<<dim3(MROWS/32), blk, 0, stream>>>(u, Bw16, Bu, log_lambda, cf);

    // 2) fused scan + y = hs . C_w^T + D*u  (32-row blocks, no Bu LDS staging)
    gemm2_scan<<<dim3(MROWS/BM2), blk, 0, stream>>>(
        Bu, Cw16, log_lambda, cf, y, Dv, u);
}